// Round 9
// baseline (256.211 us; speedup 1.0000x reference)
//
#include <hip/hip_runtime.h>

typedef unsigned short u16;
typedef __bf16 bf16x8 __attribute__((ext_vector_type(8)));
typedef float f32x4 __attribute__((ext_vector_type(4)));

#define B_    128
#define S_    416
#define NPEP  32
#define MMHC  384
#define D_    256
#define H_    8
#define E_    32
#define O_    256
#define BS_   (B_ * S_)      /* 53248 */

#define PAD_TOK (-2.0f)
#define SCALE_E 0.17677669529663687f   /* 1/sqrt(32) */

typedef const __attribute__((address_space(1))) void cg_void;
typedef __attribute__((address_space(3))) void lds_void;

__device__ __forceinline__ float bf2f(u16 u) {
  union { unsigned int i; float f; } x; x.i = ((unsigned int)u) << 16; return x.f;
}
__device__ __forceinline__ u16 f2bf(float f) {
  union { float f; unsigned int i; } x; x.f = f;
  unsigned int i = x.i;
  return (u16)((i + 0x7FFFu + ((i >> 16) & 1u)) >> 16);  // RNE
}
__device__ __forceinline__ unsigned pk2bf(float lo, float hi) {
  return (unsigned)f2bf(lo) | ((unsigned)f2bf(hi) << 16);
}

// ---------------------------------------------------------------------------
// prep = pack_w + ln1 merged (disjoint block ranges; r6: saved ~4us launch gap).
//  blocks 0..1023    : WT[col][d] = {q,k,v,g}_proj[h][d][e]
//  blocks 1024..1279 : WoT[n][k] = out_w[k][n]
//  blocks 1280..     : LN1 rows, fp32 in -> bf16 out, 4 rows/block
// ---------------------------------------------------------------------------
__global__ __launch_bounds__(256)
void prep(const float* __restrict__ q, const float* __restrict__ k,
          const float* __restrict__ v, const float* __restrict__ g,
          const float* __restrict__ ow, u16* __restrict__ WT, u16* __restrict__ WoT,
          const float* __restrict__ x, u16* __restrict__ xln,
          const float* __restrict__ gam, const float* __restrict__ bet) {
  const int bx = blockIdx.x, t = threadIdx.x;
  if (bx < 1024) {
    const int col = bx;
    const int p = col >> 8, h = (col >> 5) & 7, e = col & 31;
    const float* src = (p == 0) ? q : (p == 1) ? k : (p == 2) ? v : g;
    WT[col * 256 + t] = f2bf(src[(h * 256 + t) * 32 + e]);
    return;
  }
  if (bx < 1280) {
    const int n = bx - 1024;
    WoT[n * 256 + t] = f2bf(ow[t * 256 + n]);
    return;
  }
  const int w = t >> 6, lane = t & 63;
  const size_t row = (size_t)(bx - 1280) * 4 + w;
  const float4 u = *((const float4*)x + row * 64 + lane);
  const float x0 = u.x, x1 = u.y, x2 = u.z, x3 = u.w;
  float sum = (x0 + x1) + (x2 + x3);
  float ss  = (x0 * x0 + x1 * x1) + (x2 * x2 + x3 * x3);
  #pragma unroll
  for (int off = 32; off; off >>= 1) {
    sum += __shfl_xor(sum, off);
    ss  += __shfl_xor(ss, off);
  }
  const float mean = sum * 0.00390625f;
  float var = ss * 0.00390625f - mean * mean;
  var = fmaxf(var, 0.0f);
  const float rs = rsqrtf(var + 1e-6f);
  const float4 g4 = *((const float4*)gam + lane);
  const float4 b4 = *((const float4*)bet + lane);
  ushort4 r;
  r.x = f2bf((x0 - mean) * rs * g4.x + b4.x);
  r.y = f2bf((x1 - mean) * rs * g4.y + b4.y);
  r.z = f2bf((x2 - mean) * rs * g4.z + b4.z);
  r.w = f2bf((x3 - mean) * rs * g4.w + b4.w);
  *((ushort4*)xln + row * 64 + lane) = r;
}

// ---------------------------------------------------------------------------
// GEMM1: QKVG = xln[53248 x 256] * WT^T, head-major scatter epilogue.
// r4/r8 structure: single-buffered global_load_lds(16B), 2 barriers/K-step,
// XOR-swizzled LDS, XCD-bijective swizzle (FETCH 16MB), jn-innermost stores.
// r9 experiment (single variable): (256,2) -> (256,4). Tests whether r2's
// WRITE inflation at 4 blocks/CU was store-ORDER (jn-outer halves 16 instrs
// apart, fixed in r3) or occupancy-intrinsic. If WRITE stays ~107MB the
// doubled wave count covers the barrier drain for free.
// Design-space brackets (measured): r6 2-phase dbuf = 49us; r7 LDS-free
// direct frags = 114us. 1-phase staged is the local optimum.
// ---------------------------------------------------------------------------
__global__ __launch_bounds__(256, 4)
void gemm_qkvg(const u16* __restrict__ A, const u16* __restrict__ BT,
               u16* __restrict__ Qh, u16* __restrict__ Kh,
               u16* __restrict__ Vh, u16* __restrict__ Gh) {
  __shared__ __attribute__((aligned(16))) u16 As[128 * 64];
  __shared__ __attribute__((aligned(16))) u16 Bs[128 * 64];
  const int L = blockIdx.x;
  const int m0 = ((L & 7) + 8 * (L >> 6)) * 128;
  const int n0 = ((L >> 3) & 7) * 128;
  const int tid = threadIdx.x;
  const int lane = tid & 63;
  const int w = tid >> 6;
  const int wr = (w >> 1) * 64;
  const int wc = (w & 1) * 64;
  const int mi = lane & 15;
  const int quad = lane >> 4;
  const int rseg = lane >> 3;               // 0..7
  const int gcol = (lane & 7) ^ rseg;       // swizzled global 16B-granule
  f32x4 acc[4][4] = {};
  for (int kc = 0; kc < 256; kc += 64) {
    __syncthreads();
    #pragma unroll
    for (int j = 0; j < 4; ++j) {
      const int seg = w * 4 + j;            // 0..15, 8 rows each
      const int r = seg * 8 + rseg;
      const u16* ga = &A[(size_t)(m0 + r) * 256 + kc + gcol * 8];
      __builtin_amdgcn_global_load_lds((cg_void*)ga, (lds_void*)&As[seg * 512], 16, 0, 0);
      const u16* gb = &BT[(size_t)(n0 + r) * 256 + kc + gcol * 8];
      __builtin_amdgcn_global_load_lds((cg_void*)gb, (lds_void*)&Bs[seg * 512], 16, 0, 0);
    }
    __syncthreads();
    #pragma unroll
    for (int kt = 0; kt < 2; ++kt) {
      bf16x8 a[4], bb[4];
      #pragma unroll
      for (int i = 0; i < 4; ++i) {
        const int m = wr + i * 16 + mi;
        const int pg = (kt * 4 + quad) ^ (mi & 7);
        a[i] = *(const bf16x8*)&As[m * 64 + pg * 8];
      }
      #pragma unroll
      for (int i = 0; i < 4; ++i) {
        const int n = wc + i * 16 + mi;
        const int pg = (kt * 4 + quad) ^ (mi & 7);
        bb[i] = *(const bf16x8*)&Bs[n * 64 + pg * 8];
      }
      #pragma unroll
      for (int i = 0; i < 4; ++i)
        #pragma unroll
        for (int jn = 0; jn < 4; ++jn)
          acc[i][jn] = __builtin_amdgcn_mfma_f32_16x16x32_bf16(a[i], bb[jn], acc[i][jn], 0, 0, 0);
    }
  }
  // D: row = quad*4 + reg, col = lane&15. Scatter col -> P[h][row][e].
  u16* dstj[4];
  #pragma unroll
  for (int jn = 0; jn < 4; ++jn) {
    const int colb = n0 + wc + jn * 16;     // wave-uniform 16-block
    const int p = colb >> 8;
    const int h = (colb >> 5) & 7;
    const int e = (colb & 16) + mi;
    u16* bp = (p == 0) ? Qh : (p == 1) ? Kh : (p == 2) ? Vh : Gh;
    dstj[jn] = bp + (size_t)h * BS_ * 32 + e;
  }
  #pragma unroll
  for (int i = 0; i < 4; ++i) {
    const int row = m0 + wr + i * 16 + quad * 4;
    #pragma unroll
    for (int r = 0; r < 4; ++r) {
      #pragma unroll
      for (int jn = 0; jn < 4; ++jn)      // jn innermost: line halves adjacent
        dstj[jn][(size_t)(row + r) * 32] = f2bf(acc[i][jn][r]);
    }
  }
}

// ---------------------------------------------------------------------------
// Fused attention, TRANSPOSED-S design. One block per (b,h), 256 thr/4 waves.
//   waves 0-1 : peptide rows (16 each) attending to 384 MHC keys.
//   waves 2-3 : MHC rows (12 row-tiles of 16 each) attending to 32 pep keys.
// S^T = mfma(K, Q): lane column = one query row -> softmax reduce = 2
// shfl_xor; no row-max (|s| <~ 6, exp in range; softmax scale-invariant);
// PV B-frag built in registers via quad-exchange (8 shfl + 4 selects);
// 29.3KB LDS -> 4 blocks/CU (verified r4: att dropped 53 -> <25us).
// ---------------------------------------------------------------------------
__global__ __launch_bounds__(256, 4)
void att_fused(const u16* __restrict__ Qh, const u16* __restrict__ Kh,
               const u16* __restrict__ Vh, const u16* __restrict__ Gh,
               const float* __restrict__ p_mask, const float* __restrict__ m_mask,
               u16* __restrict__ atto) {
  __shared__ __attribute__((aligned(16))) u16 VT[32][392];   // V_mhc^T[e][y]
  __shared__ __attribute__((aligned(16))) u16 VpT[32][40];   // V_pep^T[e][y]
  __shared__ __attribute__((aligned(16))) float pf[32];
  __shared__ __attribute__((aligned(16))) float mfl[384];
  const int bh = blockIdx.x;
  const int b = bh >> 3, h = bh & 7;
  const int t = threadIdx.x;
  const int lane = t & 63, w = t >> 6;
  const int mi = lane & 15, quad = lane >> 4;
  const size_t hb = (size_t)h * BS_ + (size_t)b * S_;

  // ---- cooperative staging ----
  if (t < 32) pf[t] = (p_mask[b * NPEP + t] == PAD_TOK) ? 0.0f : 1.0f;
  mfl[t] = (m_mask[b * MMHC + t] == PAD_TOK) ? 0.0f : 1.0f;
  if (t < 128) mfl[256 + t] = (m_mask[b * MMHC + 256 + t] == PAD_TOK) ? 0.0f : 1.0f;
  {
    const int y = t >> 3, e0 = (t & 7) * 4;
    const ushort4 u = *(const ushort4*)&Vh[(hb + y) * 32 + e0];
    VpT[e0 + 0][y] = u.x; VpT[e0 + 1][y] = u.y;
    VpT[e0 + 2][y] = u.z; VpT[e0 + 3][y] = u.w;
  }
  #pragma unroll
  for (int i = 0; i < 12; ++i) {
    const int idx = i * 256 + t;            // 0..3071
    const int y = idx >> 3, e0 = (idx & 7) * 4;
    const ushort4 u = *(const ushort4*)&Vh[(hb + 32 + y) * 32 + e0];
    VT[e0 + 0][y] = u.x; VT[e0 + 1][y] = u.y;
    VT[e0 + 2][y] = u.z; VT[e0 + 3][y] = u.w;
  }
  __syncthreads();

  const f32x4 fz = {0.0f, 0.0f, 0.0f, 0.0f};
  const int idxA = ((quad & 1) * 2) * 16 + mi;  // exchange src lanes
  const int idxB = idxA + 16;
  const bool hi = quad >= 2;
  union U8 { unsigned u[4]; bf16x8 v; };

  if (w < 2) {
    // ================= peptide rows: 16 rows, 384 keys =================
    const bf16x8 aq = *(const bf16x8*)&Qh[(hb + w * 16 + mi) * 32 + quad * 8];
    float lsum = 0.0f;
    f32x4 o0 = fz, o1 = fz;
    #pragma unroll
    for (int ks = 0; ks < 12; ++ks) {
      unsigned pA0, pA1, pB0, pB1;
      {
        const int kt = 2 * ks;
        const bf16x8 bk = *(const bf16x8*)&Kh[(hb + 32 + kt * 16 + mi) * 32 + quad * 8];
        const f32x4 s = __builtin_amdgcn_mfma_f32_16x16x32_bf16(bk, aq, fz, 0, 0, 0);
        const float4 m4 = *(const float4*)&mfl[kt * 16 + quad * 4];
        const float e0 = m4.x * __expf(s[0] * SCALE_E);
        const float e1 = m4.y * __expf(s[1] * SCALE_E);
        const float e2 = m4.z * __expf(s[2] * SCALE_E);
        const float e3 = m4.w * __expf(s[3] * SCALE_E);
        lsum += (e0 + e1) + (e2 + e3);
        pA0 = pk2bf(e0, e1); pA1 = pk2bf(e2, e3);
      }
      {
        const int kt = 2 * ks + 1;
        const bf16x8 bk = *(const bf16x8*)&Kh[(hb + 32 + kt * 16 + mi) * 32 + quad * 8];
        const f32x4 s = __builtin_amdgcn_mfma_f32_16x16x32_bf16(bk, aq, fz, 0, 0, 0);
        const float4 m4 = *(const float4*)&mfl[kt * 16 + quad * 4];
        const float e0 = m4.x * __expf(s[0] * SCALE_E);
        const float e1 = m4.y * __expf(s[1] * SCALE_E);
        const float e2 = m4.z * __expf(s[2] * SCALE_E);
        const float e3 = m4.w * __expf(s[3] * SCALE_E);
        lsum += (e0 + e1) + (e2 + e3);
        pB0 = pk2bf(e0, e1); pB1 = pk2bf(e2, e3);
      }
      const unsigned a00 = __shfl(pA0, idxA), a01 = __shfl(pA1, idxA);
      const unsigned b00 = __shfl(pB0, idxA), b01 = __shfl(pB1, idxA);
      const unsigned a10 = __shfl(pA0, idxB), a11 = __shfl(pA1, idxB);
      const unsigned b10 = __shfl(pB0, idxB), b11 = __shfl(pB1, idxB);
      U8 pf_;
      pf_.u[0] = hi ? b00 : a00;
      pf_.u[1] = hi ? b01 : a01;
      pf_.u[2] = hi ? b10 : a10;
      pf_.u[3] = hi ? b11 : a11;
      const bf16x8 v0 = *(const bf16x8*)&VT[mi][ks * 32 + quad * 8];
      const bf16x8 v1 = *(const bf16x8*)&VT[16 + mi][ks * 32 + quad * 8];
      o0 = __builtin_amdgcn_mfma_f32_16x16x32_bf16(v0, pf_.v, o0, 0, 0, 0);
      o1 = __builtin_amdgcn_mfma_f32_16x16x32_bf16(v1, pf_.v, o1, 0, 0, 0);
    }
    lsum += __shfl_xor(lsum, 16);
    lsum += __shfl_xor(lsum, 32);
    const int prow = w * 16 + mi;
    const float sc = (1.0f / lsum) * pf[prow];
    const ushort4 g0 = *(const ushort4*)&Gh[(hb + prow) * 32 + quad * 4];
    const ushort4 g1 = *(const ushort4*)&Gh[(hb + prow) * 32 + 16 + quad * 4];
    ushort4 r0, r1;
    r0.x = f2bf(o0[0] * sc / (1.0f + __expf(-bf2f(g0.x))));
    r0.y = f2bf(o0[1] * sc / (1.0f + __expf(-bf2f(g0.y))));
    r0.z = f2bf(o0[2] * sc / (1.0f + __expf(-bf2f(g0.z))));
    r0.w = f2bf(o0[3] * sc / (1.0f + __expf(-bf2f(g0.w))));
    r1.x = f2bf(o1[0] * sc / (1.0f + __expf(-bf2f(g1.x))));
    r1.y = f2bf(o1[1] * sc / (1.0f + __expf(-bf2f(g1.y))));
    r1.z = f2bf(o1[2] * sc / (1.0f + __expf(-bf2f(g1.z))));
    r1.w = f2bf(o1[3] * sc / (1.0f + __expf(-bf2f(g1.w))));
    *(ushort4*)&atto[(hb + prow) * 32 + quad * 4] = r0;
    *(ushort4*)&atto[(hb + prow) * 32 + 16 + quad * 4] = r1;
  } else {
    // ================= MHC rows: 12 row-tiles x 16 rows, 32 keys ========
    const int wid = w - 2;
    const bf16x8 bk0 = *(const bf16x8*)&Kh[(hb + mi) * 32 + quad * 8];
    const bf16x8 bk1 = *(const bf16x8*)&Kh[(hb + 16 + mi) * 32 + quad * 8];
    const bf16x8 bv0 = *(const bf16x8*)&VpT[mi][quad * 8];
    const bf16x8 bv1 = *(const bf16x8*)&VpT[16 + mi][quad * 8];
    const float4 pfa = *(const float4*)&pf[quad * 4];        // keys quad*4+r
    const float4 pfb = *(const float4*)&pf[16 + quad * 4];   // keys 16+quad*4+r
    for (int i = 0; i < 12; ++i) {
      const int rloc = (i * 2 + wid) * 16;          // mhc-local row base
      const size_t grow = hb + 32 + rloc + mi;      // this lane's output row
      const bf16x8 aq = *(const bf16x8*)&Qh[grow * 32 + quad * 8];
      const f32x4 s0 = __builtin_amdgcn_mfma_f32_16x16x32_bf16(bk0, aq, fz, 0, 0, 0);
      const f32x4 s1 = __builtin_amdgcn_mfma_f32_16x16x32_bf16(bk1, aq, fz, 0, 0, 0);
      const float e00 = pfa.x * __expf(s0[0] * SCALE_E);
      const float e01 = pfa.y * __expf(s0[1] * SCALE_E);
      const float e02 = pfa.z * __expf(s0[2] * SCALE_E);
      const float e03 = pfa.w * __expf(s0[3] * SCALE_E);
      const float e10 = pfb.x * __expf(s1[0] * SCALE_E);
      const float e11 = pfb.y * __expf(s1[1] * SCALE_E);
      const float e12 = pfb.z * __expf(s1[2] * SCALE_E);
      const float e13 = pfb.w * __expf(s1[3] * SCALE_E);
      float lsum = ((e00 + e01) + (e02 + e03)) + ((e10 + e11) + (e12 + e13));
      lsum += __shfl_xor(lsum, 16);
      lsum += __shfl_xor(lsum, 32);
      const unsigned pA0 = pk2bf(e00, e01), pA1 = pk2bf(e02, e03);
      const unsigned pB0 = pk2bf(e10, e11), pB1 = pk2bf(e12, e13);
      const unsigned a00 = __shfl(pA0, idxA), a01 = __shfl(pA1, idxA);
      const unsigned b00 = __shfl(pB0, idxA), b01 = __shfl(pB1, idxA);
      const unsigned a10 = __shfl(pA0, idxB), a11 = __shfl(pA1, idxB);
      const unsigned b10 = __shfl(pB0, idxB), b11 = __shfl(pB1, idxB);
      U8 pf_;
      pf_.u[0] = hi ? b00 : a00;
      pf_.u[1] = hi ? b01 : a01;
      pf_.u[2] = hi ? b10 : a10;
      pf_.u[3] = hi ? b11 : a11;
      const f32x4 o0 = __builtin_amdgcn_mfma_f32_16x16x32_bf16(bv0, pf_.v, fz, 0, 0, 0);
      const f32x4 o1 = __builtin_amdgcn_mfma_f32_16x16x32_bf16(bv1, pf_.v, fz, 0, 0, 0);
      const float sc = (1.0f / lsum) * mfl[rloc + mi];
      const ushort4 g0 = *(const ushort4*)&Gh[grow * 32 + quad * 4];
      const ushort4 g1 = *(const ushort4*)&Gh[grow * 32 + 16 + quad * 4];
      ushort4 r0, r1;
      r0.x = f2bf(o0[0] * sc / (1.0f + __expf(-bf2f(g0.x))));
      r0.y = f2bf(o0[1] * sc / (1.0f + __expf(-bf2f(g0.y))));
      r0.z = f2bf(o0[2] * sc / (1.0f + __expf(-bf2f(g0.z))));
      r0.w = f2bf(o0[3] * sc / (1.0f + __expf(-bf2f(g0.w))));
      r1.x = f2bf(o1[0] * sc / (1.0f + __expf(-bf2f(g1.x))));
      r1.y = f2bf(o1[1] * sc / (1.0f + __expf(-bf2f(g1.y))));
      r1.z = f2bf(o1[2] * sc / (1.0f + __expf(-bf2f(g1.z))));
      r1.w = f2bf(o1[3] * sc / (1.0f + __expf(-bf2f(g1.w))));
      *(ushort4*)&atto[grow * 32 + quad * 4] = r0;
      *(ushort4*)&atto[grow * 32 + 16 + quad * 4] = r1;
    }
  }
}

// ---------------------------------------------------------------------------
// GEMM2 + bias + LN2 fused: out = LN(att[53248x256] * WoT^T + bias).
// r4/r8 structure: global_load_lds staging, (512,2).
// A is HEAD-MAJOR atto[h][row][32]; the 16B stage granules never cross a
// head boundary (col = kc + gcol*8, multiples of 8), so only the A address
// computation changes vs row-major.
// ---------------------------------------------------------------------------
__global__ __launch_bounds__(512, 2)
void gemm2_ln(const u16* __restrict__ A, const u16* __restrict__ BT,
              float* __restrict__ out, const float* __restrict__ bias,
              const float* __restrict__ gam, const float* __restrict__ bet) {
  __shared__ __attribute__((aligned(16))) u16 As[128 * 64];
  __shared__ __attribute__((aligned(16))) u16 Bs[256 * 64];
  __shared__ float rsum[128][4];
  __shared__ float rssq[128][4];
  __shared__ float mean_s[128], rstd_s[128];
  const int m0 = blockIdx.x * 128;
  const int tid = threadIdx.x;
  const int lane = tid & 63;
  const int w = tid >> 6;            // 0..7
  const int wr = (w >> 2) * 64;      // 0 / 64
  const int wc = (w & 3) * 64;       // 0,64,128,192
  const int mi = lane & 15;
  const int quad = lane >> 4;
  const int rseg = lane >> 3;
  const int gcol = (lane & 7) ^ rseg;
  f32x4 acc[4][4] = {};
  for (int kc = 0; kc < 256; kc += 64) {
    __syncthreads();
    #pragma unroll
    for (int j = 0; j < 2; ++j) {          // A: 16 segs of 8 rows
      const int seg = w * 2 + j;
      const int r = seg * 8 + rseg;
      const int c = kc + gcol * 8;         // head-major remap
      const u16* ga = &A[((size_t)(c >> 5) * BS_ + (m0 + r)) * 32 + (c & 31)];
      __builtin_amdgcn_global_load_lds((cg_void*)ga, (lds_void*)&As[seg * 512], 16, 0, 0);
    }
    #pragma unroll
    for (int j = 0; j < 4; ++j) {          // B: 32 segs of 8 rows
      const int seg = w * 4 + j;
      const int r = seg * 8 + rseg;
      const u16* gb = &BT[(size_t)r * 256 + kc + gcol * 8];
      __builtin_amdgcn_global_load_lds((cg_void*)gb, (lds_void*)&Bs[seg * 512], 16, 0, 0);
    }
    __syncthreads();
    #pragma unroll
    for (int kt = 0; kt < 2; ++kt) {
      bf16x8 a[4], bb[4];
      #pragma unroll
      for (int i = 0; i < 4; ++i) {
        const int m = wr + i * 16 + mi;
        const int pg = (kt * 4 + quad) ^ (mi & 7);
        a[i] = *(const bf16x8*)&As[m * 64 + pg * 8];
      }
      #pragma unroll
      for (int i = 0; i < 4; ++i) {
        const int n = wc + i * 16 + mi;
        const int pg = (kt * 4 + quad) ^ (mi & 7);
        bb[i] = *(const bf16x8*)&Bs[n * 64 + pg * 8];
      }
      #pragma unroll
      for (int i = 0; i < 4; ++i)
        #pragma unroll
        for (int jn = 0; jn < 4; ++jn)
          acc[i][jn] = __builtin_amdgcn_mfma_f32_16x16x32_bf16(a[i], bb[jn], acc[i][jn], 0, 0, 0);
    }
  }
  // bias per thread-column
  float bia[4];
  #pragma unroll
  for (int jn = 0; jn < 4; ++jn) bia[jn] = bias[wc + jn * 16 + mi];
  // row partial stats: sum over jn, reduce over mi (within quad)
  #pragma unroll
  for (int i = 0; i < 4; ++i) {
    #pragma unroll
    for (int r = 0; r < 4; ++r) {
      float s = 0.0f, qq = 0.0f;
      #pragma unroll
      for (int jn = 0; jn < 4; ++jn) {
        const float v = acc[i][jn][r] + bia[jn];
        s += v; qq += v * v;
      }
      #pragma unroll
      for (int off = 1; off < 16; off <<= 1) {
        s  += __shfl_xor(s, off);
        qq += __shfl_xor(qq, off);
      }
      if (mi == 0) {
        const int rl = wr + i * 16 + quad * 4 + r;
        rsum[rl][w & 3] = s;
        rssq[rl][w & 3] = qq;
      }
    }
  }
  __syncthreads();
  if (tid < 128) {
    const float s = rsum[tid][0] + rsum[tid][1] + rsum[tid][2] + rsum[tid][3];
    const float qq = rssq[tid][0] + rssq[tid][1] + rssq[tid][2] + rssq[tid][3];
    const float mean = s * 0.00390625f;
    float var = qq * 0.00390625f - mean * mean;
    var = fmaxf(var, 0.0f);
    mean_s[tid] = mean;
    rstd_s[tid] = rsqrtf(var + 1e-6f);
  }
  __syncthreads();
  #pragma unroll
  for (int jn = 0; jn < 4; ++jn) {
    const int col = wc + jn * 16 + mi;
    const float gv = gam[col], bv = bet[col];
    #pragma unroll
    for (int i = 0; i < 4; ++i) {
      #pragma unroll
      for (int r = 0; r < 4; ++r) {
        const int rl = wr + i * 16 + quad * 4 + r;
        const float v = acc[i][jn][r] + bia[jn];
        out[(size_t)(m0 + rl) * 256 + col] = (v - mean_s[rl]) * rstd_s[rl] * gv + bv;
      }
    }
  }
}

// ---------------------------------------------------------------------------
// Launch. All d_in fp32; d_out fp32. Workspace (full batch, ~137 MB):
//   WT   @ 0         : 524288   (bf16)
//   WoT  @ 524288    : 131072   (bf16)
//   attx @ 655360    : BS*256*2 = 27262976  (bf16; LN1 out row-major, then
//                       attention out HEAD-MAJOR [h][row][32])
//   Qh   @ 27918336  : 27262976 (bf16, [h][row][e])
//   Kh   @ 55181312  : 27262976
//   Vh   @ 82444288  : 27262976
//   Gh   @ 109707264 : 27262976    total 136970240
// ---------------------------------------------------------------------------
extern "C" void kernel_launch(void* const* d_in, const int* in_sizes, int n_in,
                              void* d_out, int out_size, void* d_ws, size_t ws_size,
                              hipStream_t stream) {
  const float* x      = (const float*)d_in[0];
  const float* p_mask = (const float*)d_in[1];
  const float* m_mask = (const float*)d_in[2];
  const float* q_proj = (const float*)d_in[3];
  const float* k_proj = (const float*)d_in[4];
  const float* v_proj = (const float*)d_in[5];
  const float* g_proj = (const float*)d_in[6];
  const float* out_w  = (const float*)d_in[7];
  const float* out_b  = (const float*)d_in[8];
  const float* ln1_g  = (const float*)d_in[9];
  const float* ln1_b  = (const float*)d_in[10];
  const float* ln2_g  = (const float*)d_in[11];
  const float* ln2_b  = (const float*)d_in[12];

  char* ws = (char*)d_ws;
  u16* WT   = (u16*)(ws);
  u16* WoT  = (u16*)(ws + 524288);
  u16* attx = (u16*)(ws + 655360);
  u16* Qh   = (u16*)(ws + 27918336);
  u16* Kh   = (u16*)(ws + 55181312);
  u16* Vh   = (u16*)(ws + 82444288);
  u16* Gh   = (u16*)(ws + 109707264);
  float* outp = (float*)d_out;

  hipLaunchKernelGGL(prep, dim3(1280 + BS_ / 4), dim3(256), 0, stream,
                     q_proj, k_proj, v_proj, g_proj, out_w, WT, WoT,
                     x, attx, ln1_g, ln1_b);
  hipLaunchKernelGGL(gemm_qkvg, dim3(8 * (BS_ / 128)), dim3(256), 0, stream,
                     attx, WT, Qh, Kh, Vh, Gh);
  hipLaunchKernelGGL(att_fused, dim3(B_ * H_), dim3(256), 0, stream,
                     Qh, Kh, Vh, Gh, p_mask, m_mask, attx);
  hipLaunchKernelGGL(gemm2_ln, dim3(BS_ / 128), dim3(512), 0, stream,
                     attx, WoT, outp, out_b, ln2_g, ln2_b);
}

// Round 10
// 224.656 us; speedup vs baseline: 1.1405x; 1.1405x over previous
//
#include <hip/hip_runtime.h>

typedef unsigned short u16;
typedef __bf16 bf16x8 __attribute__((ext_vector_type(8)));
typedef float f32x4 __attribute__((ext_vector_type(4)));

#define B_    128
#define S_    416
#define NPEP  32
#define MMHC  384
#define D_    256
#define H_    8
#define E_    32
#define O_    256
#define BS_   (B_ * S_)      /* 53248 */

#define PAD_TOK (-2.0f)
#define SCALE_E 0.17677669529663687f   /* 1/sqrt(32) */

typedef const __attribute__((address_space(1))) void cg_void;
typedef __attribute__((address_space(3))) void lds_void;

__device__ __forceinline__ float bf2f(u16 u) {
  union { unsigned int i; float f; } x; x.i = ((unsigned int)u) << 16; return x.f;
}
__device__ __forceinline__ u16 f2bf(float f) {
  union { float f; unsigned int i; } x; x.f = f;
  unsigned int i = x.i;
  return (u16)((i + 0x7FFFu + ((i >> 16) & 1u)) >> 16);  // RNE
}
__device__ __forceinline__ unsigned pk2bf(float lo, float hi) {
  return (unsigned)f2bf(lo) | ((unsigned)f2bf(hi) << 16);
}

// ---------------------------------------------------------------------------
// prep = pack_w + ln1 merged (disjoint block ranges).
//  blocks 0..1023    : WT[col][d] = {q,k,v,g}_proj[h][d][e]
//  blocks 1024..1279 : WoT[n][k] = out_w[k][n]
//  blocks 1280..     : LN1 rows, fp32 in -> bf16 out, 4 rows/block
// ---------------------------------------------------------------------------
__global__ __launch_bounds__(256)
void prep(const float* __restrict__ q, const float* __restrict__ k,
          const float* __restrict__ v, const float* __restrict__ g,
          const float* __restrict__ ow, u16* __restrict__ WT, u16* __restrict__ WoT,
          const float* __restrict__ x, u16* __restrict__ xln,
          const float* __restrict__ gam, const float* __restrict__ bet) {
  const int bx = blockIdx.x, t = threadIdx.x;
  if (bx < 1024) {
    const int col = bx;
    const int p = col >> 8, h = (col >> 5) & 7, e = col & 31;
    const float* src = (p == 0) ? q : (p == 1) ? k : (p == 2) ? v : g;
    WT[col * 256 + t] = f2bf(src[(h * 256 + t) * 32 + e]);
    return;
  }
  if (bx < 1280) {
    const int n = bx - 1024;
    WoT[n * 256 + t] = f2bf(ow[t * 256 + n]);
    return;
  }
  const int w = t >> 6, lane = t & 63;
  const size_t row = (size_t)(bx - 1280) * 4 + w;
  const float4 u = *((const float4*)x + row * 64 + lane);
  const float x0 = u.x, x1 = u.y, x2 = u.z, x3 = u.w;
  float sum = (x0 + x1) + (x2 + x3);
  float ss  = (x0 * x0 + x1 * x1) + (x2 * x2 + x3 * x3);
  #pragma unroll
  for (int off = 32; off; off >>= 1) {
    sum += __shfl_xor(sum, off);
    ss  += __shfl_xor(ss, off);
  }
  const float mean = sum * 0.00390625f;
  float var = ss * 0.00390625f - mean * mean;
  var = fmaxf(var, 0.0f);
  const float rs = rsqrtf(var + 1e-6f);
  const float4 g4 = *((const float4*)gam + lane);
  const float4 b4 = *((const float4*)bet + lane);
  ushort4 r;
  r.x = f2bf((x0 - mean) * rs * g4.x + b4.x);
  r.y = f2bf((x1 - mean) * rs * g4.y + b4.y);
  r.z = f2bf((x2 - mean) * rs * g4.z + b4.z);
  r.w = f2bf((x3 - mean) * rs * g4.w + b4.w);
  *((ushort4*)xln + row * 64 + lane) = r;
}

// ---------------------------------------------------------------------------
// GEMM1: QKVG = xln[53248 x 256] * WT^T, head-major scatter epilogue.
// r8 FINAL structure: single-buffered global_load_lds(16B), 2 barriers/K-step,
// XOR-swizzled LDS, XCD-bijective swizzle, (256,2), jn-innermost stores.
// Full design-space bracket (measured):
//   (256,2)+jn-inner 1-phase  : 40.4us  <- THIS (WRITE=107MB logical min)
//   (256,2) 2-phase dbuf (r6) : 49us
//   (256,4)+jn-outer (r2)     : 59us  (WRITE 148MB)
//   (256,4)+jn-inner (r9)     : 74us  (WRITE 200MB + FETCH 53MB: L2 thrash
//                               at 128 blocks/XCD is occupancy-INTRINSIC)
//   LDS-free direct frags (r7): 114us (L2 latency-bound)
// Inter-block TLP (2 blocks x 4 waves) hides the barrier drain better than
// any source-level pipelining; do not re-attempt without counted-vmcnt asm.
// ---------------------------------------------------------------------------
__global__ __launch_bounds__(256, 2)
void gemm_qkvg(const u16* __restrict__ A, const u16* __restrict__ BT,
               u16* __restrict__ Qh, u16* __restrict__ Kh,
               u16* __restrict__ Vh, u16* __restrict__ Gh) {
  __shared__ __attribute__((aligned(16))) u16 As[128 * 64];
  __shared__ __attribute__((aligned(16))) u16 Bs[128 * 64];
  const int L = blockIdx.x;
  const int m0 = ((L & 7) + 8 * (L >> 6)) * 128;
  const int n0 = ((L >> 3) & 7) * 128;
  const int tid = threadIdx.x;
  const int lane = tid & 63;
  const int w = tid >> 6;
  const int wr = (w >> 1) * 64;
  const int wc = (w & 1) * 64;
  const int mi = lane & 15;
  const int quad = lane >> 4;
  const int rseg = lane >> 3;               // 0..7
  const int gcol = (lane & 7) ^ rseg;       // swizzled global 16B-granule
  f32x4 acc[4][4] = {};
  for (int kc = 0; kc < 256; kc += 64) {
    __syncthreads();
    #pragma unroll
    for (int j = 0; j < 4; ++j) {
      const int seg = w * 4 + j;            // 0..15, 8 rows each
      const int r = seg * 8 + rseg;
      const u16* ga = &A[(size_t)(m0 + r) * 256 + kc + gcol * 8];
      __builtin_amdgcn_global_load_lds((cg_void*)ga, (lds_void*)&As[seg * 512], 16, 0, 0);
      const u16* gb = &BT[(size_t)(n0 + r) * 256 + kc + gcol * 8];
      __builtin_amdgcn_global_load_lds((cg_void*)gb, (lds_void*)&Bs[seg * 512], 16, 0, 0);
    }
    __syncthreads();
    #pragma unroll
    for (int kt = 0; kt < 2; ++kt) {
      bf16x8 a[4], bb[4];
      #pragma unroll
      for (int i = 0; i < 4; ++i) {
        const int m = wr + i * 16 + mi;
        const int pg = (kt * 4 + quad) ^ (mi & 7);
        a[i] = *(const bf16x8*)&As[m * 64 + pg * 8];
      }
      #pragma unroll
      for (int i = 0; i < 4; ++i) {
        const int n = wc + i * 16 + mi;
        const int pg = (kt * 4 + quad) ^ (mi & 7);
        bb[i] = *(const bf16x8*)&Bs[n * 64 + pg * 8];
      }
      #pragma unroll
      for (int i = 0; i < 4; ++i)
        #pragma unroll
        for (int jn = 0; jn < 4; ++jn)
          acc[i][jn] = __builtin_amdgcn_mfma_f32_16x16x32_bf16(a[i], bb[jn], acc[i][jn], 0, 0, 0);
    }
  }
  // D: row = quad*4 + reg, col = lane&15. Scatter col -> P[h][row][e].
  u16* dstj[4];
  #pragma unroll
  for (int jn = 0; jn < 4; ++jn) {
    const int colb = n0 + wc + jn * 16;     // wave-uniform 16-block
    const int p = colb >> 8;
    const int h = (colb >> 5) & 7;
    const int e = (colb & 16) + mi;
    u16* bp = (p == 0) ? Qh : (p == 1) ? Kh : (p == 2) ? Vh : Gh;
    dstj[jn] = bp + (size_t)h * BS_ * 32 + e;
  }
  #pragma unroll
  for (int i = 0; i < 4; ++i) {
    const int row = m0 + wr + i * 16 + quad * 4;
    #pragma unroll
    for (int r = 0; r < 4; ++r) {
      #pragma unroll
      for (int jn = 0; jn < 4; ++jn)      // jn innermost: line halves adjacent
        dstj[jn][(size_t)(row + r) * 32] = f2bf(acc[i][jn][r]);
    }
  }
}

// ---------------------------------------------------------------------------
// Fused attention, TRANSPOSED-S design. One block per (b,h), 256 thr/4 waves.
//   waves 0-1 : peptide rows (16 each) attending to 384 MHC keys.
//   waves 2-3 : MHC rows (12 row-tiles of 16 each) attending to 32 pep keys.
// S^T = mfma(K, Q): lane column = one query row -> softmax reduce = 2
// shfl_xor; no row-max (|s| <~ 6, exp in range; softmax scale-invariant);
// PV B-frag built in registers via quad-exchange (8 shfl + 4 selects);
// 29.3KB LDS -> 4 blocks/CU (verified r4: att dropped 53 -> <25us).
// ---------------------------------------------------------------------------
__global__ __launch_bounds__(256, 4)
void att_fused(const u16* __restrict__ Qh, const u16* __restrict__ Kh,
               const u16* __restrict__ Vh, const u16* __restrict__ Gh,
               const float* __restrict__ p_mask, const float* __restrict__ m_mask,
               u16* __restrict__ atto) {
  __shared__ __attribute__((aligned(16))) u16 VT[32][392];   // V_mhc^T[e][y]
  __shared__ __attribute__((aligned(16))) u16 VpT[32][40];   // V_pep^T[e][y]
  __shared__ __attribute__((aligned(16))) float pf[32];
  __shared__ __attribute__((aligned(16))) float mfl[384];
  const int bh = blockIdx.x;
  const int b = bh >> 3, h = bh & 7;
  const int t = threadIdx.x;
  const int lane = t & 63, w = t >> 6;
  const int mi = lane & 15, quad = lane >> 4;
  const size_t hb = (size_t)h * BS_ + (size_t)b * S_;

  // ---- cooperative staging ----
  if (t < 32) pf[t] = (p_mask[b * NPEP + t] == PAD_TOK) ? 0.0f : 1.0f;
  mfl[t] = (m_mask[b * MMHC + t] == PAD_TOK) ? 0.0f : 1.0f;
  if (t < 128) mfl[256 + t] = (m_mask[b * MMHC + 256 + t] == PAD_TOK) ? 0.0f : 1.0f;
  {
    const int y = t >> 3, e0 = (t & 7) * 4;
    const ushort4 u = *(const ushort4*)&Vh[(hb + y) * 32 + e0];
    VpT[e0 + 0][y] = u.x; VpT[e0 + 1][y] = u.y;
    VpT[e0 + 2][y] = u.z; VpT[e0 + 3][y] = u.w;
  }
  #pragma unroll
  for (int i = 0; i < 12; ++i) {
    const int idx = i * 256 + t;            // 0..3071
    const int y = idx >> 3, e0 = (idx & 7) * 4;
    const ushort4 u = *(const ushort4*)&Vh[(hb + 32 + y) * 32 + e0];
    VT[e0 + 0][y] = u.x; VT[e0 + 1][y] = u.y;
    VT[e0 + 2][y] = u.z; VT[e0 + 3][y] = u.w;
  }
  __syncthreads();

  const f32x4 fz = {0.0f, 0.0f, 0.0f, 0.0f};
  const int idxA = ((quad & 1) * 2) * 16 + mi;  // exchange src lanes
  const int idxB = idxA + 16;
  const bool hi = quad >= 2;
  union U8 { unsigned u[4]; bf16x8 v; };

  if (w < 2) {
    // ================= peptide rows: 16 rows, 384 keys =================
    const bf16x8 aq = *(const bf16x8*)&Qh[(hb + w * 16 + mi) * 32 + quad * 8];
    float lsum = 0.0f;
    f32x4 o0 = fz, o1 = fz;
    #pragma unroll
    for (int ks = 0; ks < 12; ++ks) {
      unsigned pA0, pA1, pB0, pB1;
      {
        const int kt = 2 * ks;
        const bf16x8 bk = *(const bf16x8*)&Kh[(hb + 32 + kt * 16 + mi) * 32 + quad * 8];
        const f32x4 s = __builtin_amdgcn_mfma_f32_16x16x32_bf16(bk, aq, fz, 0, 0, 0);
        const float4 m4 = *(const float4*)&mfl[kt * 16 + quad * 4];
        const float e0 = m4.x * __expf(s[0] * SCALE_E);
        const float e1 = m4.y * __expf(s[1] * SCALE_E);
        const float e2 = m4.z * __expf(s[2] * SCALE_E);
        const float e3 = m4.w * __expf(s[3] * SCALE_E);
        lsum += (e0 + e1) + (e2 + e3);
        pA0 = pk2bf(e0, e1); pA1 = pk2bf(e2, e3);
      }
      {
        const int kt = 2 * ks + 1;
        const bf16x8 bk = *(const bf16x8*)&Kh[(hb + 32 + kt * 16 + mi) * 32 + quad * 8];
        const f32x4 s = __builtin_amdgcn_mfma_f32_16x16x32_bf16(bk, aq, fz, 0, 0, 0);
        const float4 m4 = *(const float4*)&mfl[kt * 16 + quad * 4];
        const float e0 = m4.x * __expf(s[0] * SCALE_E);
        const float e1 = m4.y * __expf(s[1] * SCALE_E);
        const float e2 = m4.z * __expf(s[2] * SCALE_E);
        const float e3 = m4.w * __expf(s[3] * SCALE_E);
        lsum += (e0 + e1) + (e2 + e3);
        pB0 = pk2bf(e0, e1); pB1 = pk2bf(e2, e3);
      }
      const unsigned a00 = __shfl(pA0, idxA), a01 = __shfl(pA1, idxA);
      const unsigned b00 = __shfl(pB0, idxA), b01 = __shfl(pB1, idxA);
      const unsigned a10 = __shfl(pA0, idxB), a11 = __shfl(pA1, idxB);
      const unsigned b10 = __shfl(pB0, idxB), b11 = __shfl(pB1, idxB);
      U8 pf_;
      pf_.u[0] = hi ? b00 : a00;
      pf_.u[1] = hi ? b01 : a01;
      pf_.u[2] = hi ? b10 : a10;
      pf_.u[3] = hi ? b11 : a11;
      const bf16x8 v0 = *(const bf16x8*)&VT[mi][ks * 32 + quad * 8];
      const bf16x8 v1 = *(const bf16x8*)&VT[16 + mi][ks * 32 + quad * 8];
      o0 = __builtin_amdgcn_mfma_f32_16x16x32_bf16(v0, pf_.v, o0, 0, 0, 0);
      o1 = __builtin_amdgcn_mfma_f32_16x16x32_bf16(v1, pf_.v, o1, 0, 0, 0);
    }
    lsum += __shfl_xor(lsum, 16);
    lsum += __shfl_xor(lsum, 32);
    const int prow = w * 16 + mi;
    const float sc = (1.0f / lsum) * pf[prow];
    const ushort4 g0 = *(const ushort4*)&Gh[(hb + prow) * 32 + quad * 4];
    const ushort4 g1 = *(const ushort4*)&Gh[(hb + prow) * 32 + 16 + quad * 4];
    ushort4 r0, r1;
    r0.x = f2bf(o0[0] * sc / (1.0f + __expf(-bf2f(g0.x))));
    r0.y = f2bf(o0[1] * sc / (1.0f + __expf(-bf2f(g0.y))));
    r0.z = f2bf(o0[2] * sc / (1.0f + __expf(-bf2f(g0.z))));
    r0.w = f2bf(o0[3] * sc / (1.0f + __expf(-bf2f(g0.w))));
    r1.x = f2bf(o1[0] * sc / (1.0f + __expf(-bf2f(g1.x))));
    r1.y = f2bf(o1[1] * sc / (1.0f + __expf(-bf2f(g1.y))));
    r1.z = f2bf(o1[2] * sc / (1.0f + __expf(-bf2f(g1.z))));
    r1.w = f2bf(o1[3] * sc / (1.0f + __expf(-bf2f(g1.w))));
    *(ushort4*)&atto[(hb + prow) * 32 + quad * 4] = r0;
    *(ushort4*)&atto[(hb + prow) * 32 + 16 + quad * 4] = r1;
  } else {
    // ================= MHC rows: 12 row-tiles x 16 rows, 32 keys ========
    const int wid = w - 2;
    const bf16x8 bk0 = *(const bf16x8*)&Kh[(hb + mi) * 32 + quad * 8];
    const bf16x8 bk1 = *(const bf16x8*)&Kh[(hb + 16 + mi) * 32 + quad * 8];
    const bf16x8 bv0 = *(const bf16x8*)&VpT[mi][quad * 8];
    const bf16x8 bv1 = *(const bf16x8*)&VpT[16 + mi][quad * 8];
    const float4 pfa = *(const float4*)&pf[quad * 4];        // keys quad*4+r
    const float4 pfb = *(const float4*)&pf[16 + quad * 4];   // keys 16+quad*4+r
    for (int i = 0; i < 12; ++i) {
      const int rloc = (i * 2 + wid) * 16;          // mhc-local row base
      const size_t grow = hb + 32 + rloc + mi;      // this lane's output row
      const bf16x8 aq = *(const bf16x8*)&Qh[grow * 32 + quad * 8];
      const f32x4 s0 = __builtin_amdgcn_mfma_f32_16x16x32_bf16(bk0, aq, fz, 0, 0, 0);
      const f32x4 s1 = __builtin_amdgcn_mfma_f32_16x16x32_bf16(bk1, aq, fz, 0, 0, 0);
      const float e00 = pfa.x * __expf(s0[0] * SCALE_E);
      const float e01 = pfa.y * __expf(s0[1] * SCALE_E);
      const float e02 = pfa.z * __expf(s0[2] * SCALE_E);
      const float e03 = pfa.w * __expf(s0[3] * SCALE_E);
      const float e10 = pfb.x * __expf(s1[0] * SCALE_E);
      const float e11 = pfb.y * __expf(s1[1] * SCALE_E);
      const float e12 = pfb.z * __expf(s1[2] * SCALE_E);
      const float e13 = pfb.w * __expf(s1[3] * SCALE_E);
      float lsum = ((e00 + e01) + (e02 + e03)) + ((e10 + e11) + (e12 + e13));
      lsum += __shfl_xor(lsum, 16);
      lsum += __shfl_xor(lsum, 32);
      const unsigned pA0 = pk2bf(e00, e01), pA1 = pk2bf(e02, e03);
      const unsigned pB0 = pk2bf(e10, e11), pB1 = pk2bf(e12, e13);
      const unsigned a00 = __shfl(pA0, idxA), a01 = __shfl(pA1, idxA);
      const unsigned b00 = __shfl(pB0, idxA), b01 = __shfl(pB1, idxA);
      const unsigned a10 = __shfl(pA0, idxB), a11 = __shfl(pA1, idxB);
      const unsigned b10 = __shfl(pB0, idxB), b11 = __shfl(pB1, idxB);
      U8 pf_;
      pf_.u[0] = hi ? b00 : a00;
      pf_.u[1] = hi ? b01 : a01;
      pf_.u[2] = hi ? b10 : a10;
      pf_.u[3] = hi ? b11 : a11;
      const f32x4 o0 = __builtin_amdgcn_mfma_f32_16x16x32_bf16(bv0, pf_.v, fz, 0, 0, 0);
      const f32x4 o1 = __builtin_amdgcn_mfma_f32_16x16x32_bf16(bv1, pf_.v, fz, 0, 0, 0);
      const float sc = (1.0f / lsum) * mfl[rloc + mi];
      const ushort4 g0 = *(const ushort4*)&Gh[grow * 32 + quad * 4];
      const ushort4 g1 = *(const ushort4*)&Gh[grow * 32 + 16 + quad * 4];
      ushort4 r0, r1;
      r0.x = f2bf(o0[0] * sc / (1.0f + __expf(-bf2f(g0.x))));
      r0.y = f2bf(o0[1] * sc / (1.0f + __expf(-bf2f(g0.y))));
      r0.z = f2bf(o0[2] * sc / (1.0f + __expf(-bf2f(g0.z))));
      r0.w = f2bf(o0[3] * sc / (1.0f + __expf(-bf2f(g0.w))));
      r1.x = f2bf(o1[0] * sc / (1.0f + __expf(-bf2f(g1.x))));
      r1.y = f2bf(o1[1] * sc / (1.0f + __expf(-bf2f(g1.y))));
      r1.z = f2bf(o1[2] * sc / (1.0f + __expf(-bf2f(g1.z))));
      r1.w = f2bf(o1[3] * sc / (1.0f + __expf(-bf2f(g1.w))));
      *(ushort4*)&atto[grow * 32 + quad * 4] = r0;
      *(ushort4*)&atto[grow * 32 + 16 + quad * 4] = r1;
    }
  }
}

// ---------------------------------------------------------------------------
// GEMM2 + bias + LN2 fused: out = LN(att[53248x256] * WoT^T + bias).
// r8 structure: global_load_lds staging, (512,2).
// A is HEAD-MAJOR atto[h][row][32]; the 16B stage granules never cross a
// head boundary (col = kc + gcol*8, multiples of 8), so only the A address
// computation changes vs row-major.
// ---------------------------------------------------------------------------
__global__ __launch_bounds__(512, 2)
void gemm2_ln(const u16* __restrict__ A, const u16* __restrict__ BT,
              float* __restrict__ out, const float* __restrict__ bias,
              const float* __restrict__ gam, const float* __restrict__ bet) {
  __shared__ __attribute__((aligned(16))) u16 As[128 * 64];
  __shared__ __attribute__((aligned(16))) u16 Bs[256 * 64];
  __shared__ float rsum[128][4];
  __shared__ float rssq[128][4];
  __shared__ float mean_s[128], rstd_s[128];
  const int m0 = blockIdx.x * 128;
  const int tid = threadIdx.x;
  const int lane = tid & 63;
  const int w = tid >> 6;            // 0..7
  const int wr = (w >> 2) * 64;      // 0 / 64
  const int wc = (w & 3) * 64;       // 0,64,128,192
  const int mi = lane & 15;
  const int quad = lane >> 4;
  const int rseg = lane >> 3;
  const int gcol = (lane & 7) ^ rseg;
  f32x4 acc[4][4] = {};
  for (int kc = 0; kc < 256; kc += 64) {
    __syncthreads();
    #pragma unroll
    for (int j = 0; j < 2; ++j) {          // A: 16 segs of 8 rows
      const int seg = w * 2 + j;
      const int r = seg * 8 + rseg;
      const int c = kc + gcol * 8;         // head-major remap
      const u16* ga = &A[((size_t)(c >> 5) * BS_ + (m0 + r)) * 32 + (c & 31)];
      __builtin_amdgcn_global_load_lds((cg_void*)ga, (lds_void*)&As[seg * 512], 16, 0, 0);
    }
    #pragma unroll
    for (int j = 0; j < 4; ++j) {          // B: 32 segs of 8 rows
      const int seg = w * 4 + j;
      const int r = seg * 8 + rseg;
      const u16* gb = &BT[(size_t)r * 256 + kc + gcol * 8];
      __builtin_amdgcn_global_load_lds((cg_void*)gb, (lds_void*)&Bs[seg * 512], 16, 0, 0);
    }
    __syncthreads();
    #pragma unroll
    for (int kt = 0; kt < 2; ++kt) {
      bf16x8 a[4], bb[4];
      #pragma unroll
      for (int i = 0; i < 4; ++i) {
        const int m = wr + i * 16 + mi;
        const int pg = (kt * 4 + quad) ^ (mi & 7);
        a[i] = *(const bf16x8*)&As[m * 64 + pg * 8];
      }
      #pragma unroll
      for (int i = 0; i < 4; ++i) {
        const int n = wc + i * 16 + mi;
        const int pg = (kt * 4 + quad) ^ (mi & 7);
        bb[i] = *(const bf16x8*)&Bs[n * 64 + pg * 8];
      }
      #pragma unroll
      for (int i = 0; i < 4; ++i)
        #pragma unroll
        for (int jn = 0; jn < 4; ++jn)
          acc[i][jn] = __builtin_amdgcn_mfma_f32_16x16x32_bf16(a[i], bb[jn], acc[i][jn], 0, 0, 0);
    }
  }
  // bias per thread-column
  float bia[4];
  #pragma unroll
  for (int jn = 0; jn < 4; ++jn) bia[jn] = bias[wc + jn * 16 + mi];
  // row partial stats: sum over jn, reduce over mi (within quad)
  #pragma unroll
  for (int i = 0; i < 4; ++i) {
    #pragma unroll
    for (int r = 0; r < 4; ++r) {
      float s = 0.0f, qq = 0.0f;
      #pragma unroll
      for (int jn = 0; jn < 4; ++jn) {
        const float v = acc[i][jn][r] + bia[jn];
        s += v; qq += v * v;
      }
      #pragma unroll
      for (int off = 1; off < 16; off <<= 1) {
        s  += __shfl_xor(s, off);
        qq += __shfl_xor(qq, off);
      }
      if (mi == 0) {
        const int rl = wr + i * 16 + quad * 4 + r;
        rsum[rl][w & 3] = s;
        rssq[rl][w & 3] = qq;
      }
    }
  }
  __syncthreads();
  if (tid < 128) {
    const float s = rsum[tid][0] + rsum[tid][1] + rsum[tid][2] + rsum[tid][3];
    const float qq = rssq[tid][0] + rssq[tid][1] + rssq[tid][2] + rssq[tid][3];
    const float mean = s * 0.00390625f;
    float var = qq * 0.00390625f - mean * mean;
    var = fmaxf(var, 0.0f);
    mean_s[tid] = mean;
    rstd_s[tid] = rsqrtf(var + 1e-6f);
  }
  __syncthreads();
  #pragma unroll
  for (int jn = 0; jn < 4; ++jn) {
    const int col = wc + jn * 16 + mi;
    const float gv = gam[col], bv = bet[col];
    #pragma unroll
    for (int i = 0; i < 4; ++i) {
      #pragma unroll
      for (int r = 0; r < 4; ++r) {
        const int rl = wr + i * 16 + quad * 4 + r;
        const float v = acc[i][jn][r] + bia[jn];
        out[(size_t)(m0 + rl) * 256 + col] = (v - mean_s[rl]) * rstd_s[rl] * gv + bv;
      }
    }
  }
}

// ---------------------------------------------------------------------------
// Launch. All d_in fp32; d_out fp32. Workspace (full batch, ~137 MB):
//   WT   @ 0         : 524288   (bf16)
//   WoT  @ 524288    : 131072   (bf16)
//   attx @ 655360    : BS*256*2 = 27262976  (bf16; LN1 out row-major, then
//                       attention out HEAD-MAJOR [h][row][32])
//   Qh   @ 27918336  : 27262976 (bf16, [h][row][e])
//   Kh   @ 55181312  : 27262976
//   Vh   @ 82444288  : 27262976
//   Gh   @ 109707264 : 27262976    total 136970240
// ---------------------------------------------------------------------------
extern "C" void kernel_launch(void* const* d_in, const int* in_sizes, int n_in,
                              void* d_out, int out_size, void* d_ws, size_t ws_size,
                              hipStream_t stream) {
  const float* x      = (const float*)d_in[0];
  const float* p_mask = (const float*)d_in[1];
  const float* m_mask = (const float*)d_in[2];
  const float* q_proj = (const float*)d_in[3];
  const float* k_proj = (const float*)d_in[4];
  const float* v_proj = (const float*)d_in[5];
  const float* g_proj = (const float*)d_in[6];
  const float* out_w  = (const float*)d_in[7];
  const float* out_b  = (const float*)d_in[8];
  const float* ln1_g  = (const float*)d_in[9];
  const float* ln1_b  = (const float*)d_in[10];
  const float* ln2_g  = (const float*)d_in[11];
  const float* ln2_b  = (const float*)d_in[12];

  char* ws = (char*)d_ws;
  u16* WT   = (u16*)(ws);
  u16* WoT  = (u16*)(ws + 524288);
  u16* attx = (u16*)(ws + 655360);
  u16* Qh   = (u16*)(ws + 27918336);
  u16* Kh   = (u16*)(ws + 55181312);
  u16* Vh   = (u16*)(ws + 82444288);
  u16* Gh   = (u16*)(ws + 109707264);
  float* outp = (float*)d_out;

  hipLaunchKernelGGL(prep, dim3(1280 + BS_ / 4), dim3(256), 0, stream,
                     q_proj, k_proj, v_proj, g_proj, out_w, WT, WoT,
                     x, attx, ln1_g, ln1_b);
  hipLaunchKernelGGL(gemm_qkvg, dim3(8 * (BS_ / 128)), dim3(256), 0, stream,
                     attx, WT, Qh, Kh, Vh, Gh);
  hipLaunchKernelGGL(att_fused, dim3(B_ * H_), dim3(256), 0, stream,
                     Qh, Kh, Vh, Gh, p_mask, m_mask, attx);
  hipLaunchKernelGGL(gemm2_ln, dim3(BS_ / 128), dim3(512), 0, stream,
                     attx, WoT, outp, out_b, ln2_g, ln2_b);
}

// Round 11
// 218.428 us; speedup vs baseline: 1.1730x; 1.0285x over previous
//
#include <hip/hip_runtime.h>

typedef unsigned short u16;
typedef __bf16 bf16x8 __attribute__((ext_vector_type(8)));
typedef float f32x4 __attribute__((ext_vector_type(4)));

#define B_    128
#define S_    416
#define NPEP  32
#define MMHC  384
#define D_    256
#define H_    8
#define E_    32
#define O_    256
#define BS_   (B_ * S_)      /* 53248 */

#define PAD_TOK (-2.0f)
#define SCALE_E 0.17677669529663687f   /* 1/sqrt(32) */

typedef const __attribute__((address_space(1))) void cg_void;
typedef __attribute__((address_space(3))) void lds_void;

__device__ __forceinline__ float bf2f(u16 u) {
  union { unsigned int i; float f; } x; x.i = ((unsigned int)u) << 16; return x.f;
}
__device__ __forceinline__ u16 f2bf(float f) {
  union { float f; unsigned int i; } x; x.f = f;
  unsigned int i = x.i;
  return (u16)((i + 0x7FFFu + ((i >> 16) & 1u)) >> 16);  // RNE
}
__device__ __forceinline__ unsigned pk2bf(float lo, float hi) {
  return (unsigned)f2bf(lo) | ((unsigned)f2bf(hi) << 16);
}

// ---------------------------------------------------------------------------
// prep = pack_w + ln1 merged (disjoint block ranges).
//  blocks 0..1023    : WT[col][d] = {q,k,v,g}_proj[h][d][e]
//  blocks 1024..1279 : WoT[n][k] = out_w[k][n]
//  blocks 1280..     : LN1 rows, fp32 in -> bf16 out, 4 rows/block
// ---------------------------------------------------------------------------
__global__ __launch_bounds__(256)
void prep(const float* __restrict__ q, const float* __restrict__ k,
          const float* __restrict__ v, const float* __restrict__ g,
          const float* __restrict__ ow, u16* __restrict__ WT, u16* __restrict__ WoT,
          const float* __restrict__ x, u16* __restrict__ xln,
          const float* __restrict__ gam, const float* __restrict__ bet) {
  const int bx = blockIdx.x, t = threadIdx.x;
  if (bx < 1024) {
    const int col = bx;
    const int p = col >> 8, h = (col >> 5) & 7, e = col & 31;
    const float* src = (p == 0) ? q : (p == 1) ? k : (p == 2) ? v : g;
    WT[col * 256 + t] = f2bf(src[(h * 256 + t) * 32 + e]);
    return;
  }
  if (bx < 1280) {
    const int n = bx - 1024;
    WoT[n * 256 + t] = f2bf(ow[t * 256 + n]);
    return;
  }
  const int w = t >> 6, lane = t & 63;
  const size_t row = (size_t)(bx - 1280) * 4 + w;
  const float4 u = *((const float4*)x + row * 64 + lane);
  const float x0 = u.x, x1 = u.y, x2 = u.z, x3 = u.w;
  float sum = (x0 + x1) + (x2 + x3);
  float ss  = (x0 * x0 + x1 * x1) + (x2 * x2 + x3 * x3);
  #pragma unroll
  for (int off = 32; off; off >>= 1) {
    sum += __shfl_xor(sum, off);
    ss  += __shfl_xor(ss, off);
  }
  const float mean = sum * 0.00390625f;
  float var = ss * 0.00390625f - mean * mean;
  var = fmaxf(var, 0.0f);
  const float rs = rsqrtf(var + 1e-6f);
  const float4 g4 = *((const float4*)gam + lane);
  const float4 b4 = *((const float4*)bet + lane);
  ushort4 r;
  r.x = f2bf((x0 - mean) * rs * g4.x + b4.x);
  r.y = f2bf((x1 - mean) * rs * g4.y + b4.y);
  r.z = f2bf((x2 - mean) * rs * g4.z + b4.z);
  r.w = f2bf((x3 - mean) * rs * g4.w + b4.w);
  *((ushort4*)xln + row * 64 + lane) = r;
}

// ---------------------------------------------------------------------------
// FUSED GEMM1 + attention. One block per (b,h), 512 thr / 8 waves, 1 blk/CU.
// Deletes the K/V global round-trip (~190MB HBM) of the split design
// (gemm_qkvg 40.4us + att_fused ~20us, r10).
//
// XCD mapping: b = (bid&7)*16 + (bid>>6), h = (bid>>3)&7 -> each XCD owns
// b in [16c,16c+16); the 8 head-blocks of a b run consecutively on one XCD
// so x_b (213KB) is staged from its L2 after first touch.
//
// GEMM phase (13 chunks x 32 rows):
//   stage xs[32][256] via global_load_lds(16B) with the PROVEN slot algebra:
//   LDS slot s of (row r, 64-col group) holds source granule s^(r&7);
//   frag read slot pg = ((kc&1)*4+quad)^(mi&7)  (bit-identical to gemm_qkvg).
//   Wave w: projection p=w&3 (Q,K,V,G), m-half mt=w>>2. W B-frags (16) held
//   in 64 VGPRs, preloaded from L2-resident WT -> each A-frag read feeds 2
//   MFMAs. Accumulation order kc=0..7 == gemm_qkvg's (kc64,kt) order.
//   Epilogue: Q,G -> global (same-block L2-hot round-trip);
//             K -> Kl[416][40] LDS (80B rows: 16B-aligned frags, 2-way banks);
//             V -> VT[32][392] / VpT[32][40] transposed (existing layouts).
// Attention phase: r10 att_fused verbatim (transposed-S, no row-max,
// register quad-exchange P), re-sourced: K/V from LDS, Q/G from global;
// 2 pep waves + 6 mhc waves x 4 tiles.
// LDS 77KB, (512,2) -> 1 blk/CU (8 waves = same GEMM wave count as r10).
// ---------------------------------------------------------------------------
__global__ __launch_bounds__(512, 2)
void qkvg_att(const u16* __restrict__ xln, const u16* __restrict__ WT,
              u16* __restrict__ Qh, u16* __restrict__ Gh,
              const float* __restrict__ p_mask, const float* __restrict__ m_mask,
              u16* __restrict__ atto) {
  __shared__ __attribute__((aligned(16))) u16 xs[32 * 256];
  __shared__ __attribute__((aligned(16))) u16 Kl[416][40];
  __shared__ __attribute__((aligned(16))) u16 VT[32][392];
  __shared__ __attribute__((aligned(16))) u16 VpT[32][40];
  __shared__ __attribute__((aligned(16))) float pf[32];
  __shared__ __attribute__((aligned(16))) float mfl[384];
  const int bid = blockIdx.x;
  const int b = (bid & 7) * 16 + (bid >> 6);
  const int h = (bid >> 3) & 7;
  const int t = threadIdx.x;
  const int lane = t & 63, w = t >> 6;
  const int mi = lane & 15, quad = lane >> 4;
  const size_t hb = (size_t)h * BS_ + (size_t)b * S_;

  if (t < 32) pf[t] = (p_mask[b * NPEP + t] == PAD_TOK) ? 0.0f : 1.0f;
  if (t < 384) mfl[t] = (m_mask[b * MMHC + t] == PAD_TOK) ? 0.0f : 1.0f;

  // ---- W preload: wave w -> projection p, m-half mt ----
  const int p = w & 3, mt = w >> 2;
  bf16x8 wf0[8], wf1[8];
  #pragma unroll
  for (int kc = 0; kc < 8; ++kc) {
    wf0[kc] = *(const bf16x8*)&WT[(size_t)(p * 256 + h * 32 + mi) * 256 + kc * 32 + quad * 8];
    wf1[kc] = *(const bf16x8*)&WT[(size_t)(p * 256 + h * 32 + 16 + mi) * 256 + kc * 32 + quad * 8];
  }

  // ---- GEMM phase ----
  const size_t xb = (size_t)b * S_ * 256;
  for (int c = 0; c < 13; ++c) {
    __syncthreads();                          // prior chunk's xs reads done
    #pragma unroll
    for (int i = 0; i < 2; ++i) {
      const int g0 = w * 128 + i * 64;        // wave-uniform base granule
      const int gi = g0 + lane;
      const int r = gi >> 5, sub = gi & 31;
      const int gs = (sub & 7) ^ (r & 7);     // pre-swizzled source granule
      const u16* src = &xln[xb + (size_t)(c * 32 + r) * 256 + (sub >> 3) * 64 + gs * 8];
      __builtin_amdgcn_global_load_lds((cg_void*)src, (lds_void*)&xs[g0 * 8], 16, 0, 0);
    }
    __syncthreads();                          // xs ready
    const int m0 = c * 32 + mt * 16;
    f32x4 a0 = {0.0f, 0.0f, 0.0f, 0.0f};
    f32x4 a1 = {0.0f, 0.0f, 0.0f, 0.0f};
    #pragma unroll
    for (int kc = 0; kc < 8; ++kc) {
      const int pg = ((kc & 1) * 4 + quad) ^ (mi & 7);
      const bf16x8 xa = *(const bf16x8*)&xs[(mt * 16 + mi) * 256 + (kc >> 1) * 64 + pg * 8];
      a0 = __builtin_amdgcn_mfma_f32_16x16x32_bf16(xa, wf0[kc], a0, 0, 0, 0);
      a1 = __builtin_amdgcn_mfma_f32_16x16x32_bf16(xa, wf1[kc], a1, 0, 0, 0);
    }
    // D: row = quad*4+r, col = mi (e within 16-block). p is wave-uniform.
    if (p == 0) {
      #pragma unroll
      for (int r = 0; r < 4; ++r) {
        const size_t row = hb + m0 + quad * 4 + r;
        Qh[row * 32 + mi] = f2bf(a0[r]);
        Qh[row * 32 + 16 + mi] = f2bf(a1[r]);
      }
    } else if (p == 1) {
      #pragma unroll
      for (int r = 0; r < 4; ++r) {
        const int row = m0 + quad * 4 + r;
        Kl[row][mi] = f2bf(a0[r]);
        Kl[row][16 + mi] = f2bf(a1[r]);
      }
    } else if (p == 2) {
      if (c == 0) {
        #pragma unroll
        for (int r = 0; r < 4; ++r) {
          const int row = m0 + quad * 4 + r;
          VpT[mi][row] = f2bf(a0[r]);
          VpT[16 + mi][row] = f2bf(a1[r]);
        }
      } else {
        #pragma unroll
        for (int r = 0; r < 4; ++r) {
          const int row = m0 + quad * 4 + r - 32;
          VT[mi][row] = f2bf(a0[r]);
          VT[16 + mi][row] = f2bf(a1[r]);
        }
      }
    } else {
      #pragma unroll
      for (int r = 0; r < 4; ++r) {
        const size_t row = hb + m0 + quad * 4 + r;
        Gh[row * 32 + mi] = f2bf(a0[r]);
        Gh[row * 32 + 16 + mi] = f2bf(a1[r]);
      }
    }
  }
  __syncthreads();   // Kl/VT/VpT complete; Q/G stores drained (vmcnt in barrier)

  // ---- attention phase (r10 att_fused, re-sourced) ----
  const f32x4 fz = {0.0f, 0.0f, 0.0f, 0.0f};
  const int idxA = ((quad & 1) * 2) * 16 + mi;  // exchange src lanes
  const int idxB = idxA + 16;
  const bool hi = quad >= 2;
  union U8 { unsigned u[4]; bf16x8 v; };

  if (w < 2) {
    // ================= peptide rows: 16 rows, 384 keys =================
    const bf16x8 aq = *(const bf16x8*)&Qh[(hb + w * 16 + mi) * 32 + quad * 8];
    float lsum = 0.0f;
    f32x4 o0 = fz, o1 = fz;
    #pragma unroll
    for (int ks = 0; ks < 12; ++ks) {
      unsigned pA0, pA1, pB0, pB1;
      {
        const int kt = 2 * ks;
        const bf16x8 bk = *(const bf16x8*)&Kl[32 + kt * 16 + mi][quad * 8];
        const f32x4 s = __builtin_amdgcn_mfma_f32_16x16x32_bf16(bk, aq, fz, 0, 0, 0);
        const float4 m4 = *(const float4*)&mfl[kt * 16 + quad * 4];
        const float e0 = m4.x * __expf(s[0] * SCALE_E);
        const float e1 = m4.y * __expf(s[1] * SCALE_E);
        const float e2 = m4.z * __expf(s[2] * SCALE_E);
        const float e3 = m4.w * __expf(s[3] * SCALE_E);
        lsum += (e0 + e1) + (e2 + e3);
        pA0 = pk2bf(e0, e1); pA1 = pk2bf(e2, e3);
      }
      {
        const int kt = 2 * ks + 1;
        const bf16x8 bk = *(const bf16x8*)&Kl[32 + kt * 16 + mi][quad * 8];
        const f32x4 s = __builtin_amdgcn_mfma_f32_16x16x32_bf16(bk, aq, fz, 0, 0, 0);
        const float4 m4 = *(const float4*)&mfl[kt * 16 + quad * 4];
        const float e0 = m4.x * __expf(s[0] * SCALE_E);
        const float e1 = m4.y * __expf(s[1] * SCALE_E);
        const float e2 = m4.z * __expf(s[2] * SCALE_E);
        const float e3 = m4.w * __expf(s[3] * SCALE_E);
        lsum += (e0 + e1) + (e2 + e3);
        pB0 = pk2bf(e0, e1); pB1 = pk2bf(e2, e3);
      }
      const unsigned a00 = __shfl(pA0, idxA), a01 = __shfl(pA1, idxA);
      const unsigned b00 = __shfl(pB0, idxA), b01 = __shfl(pB1, idxA);
      const unsigned a10 = __shfl(pA0, idxB), a11 = __shfl(pA1, idxB);
      const unsigned b10 = __shfl(pB0, idxB), b11 = __shfl(pB1, idxB);
      U8 pf_;
      pf_.u[0] = hi ? b00 : a00;
      pf_.u[1] = hi ? b01 : a01;
      pf_.u[2] = hi ? b10 : a10;
      pf_.u[3] = hi ? b11 : a11;
      const bf16x8 v0 = *(const bf16x8*)&VT[mi][ks * 32 + quad * 8];
      const bf16x8 v1 = *(const bf16x8*)&VT[16 + mi][ks * 32 + quad * 8];
      o0 = __builtin_amdgcn_mfma_f32_16x16x32_bf16(v0, pf_.v, o0, 0, 0, 0);
      o1 = __builtin_amdgcn_mfma_f32_16x16x32_bf16(v1, pf_.v, o1, 0, 0, 0);
    }
    lsum += __shfl_xor(lsum, 16);
    lsum += __shfl_xor(lsum, 32);
    const int prow = w * 16 + mi;
    const float sc = (1.0f / lsum) * pf[prow];
    const ushort4 g0 = *(const ushort4*)&Gh[(hb + prow) * 32 + quad * 4];
    const ushort4 g1 = *(const ushort4*)&Gh[(hb + prow) * 32 + 16 + quad * 4];
    ushort4 r0, r1;
    r0.x = f2bf(o0[0] * sc / (1.0f + __expf(-bf2f(g0.x))));
    r0.y = f2bf(o0[1] * sc / (1.0f + __expf(-bf2f(g0.y))));
    r0.z = f2bf(o0[2] * sc / (1.0f + __expf(-bf2f(g0.z))));
    r0.w = f2bf(o0[3] * sc / (1.0f + __expf(-bf2f(g0.w))));
    r1.x = f2bf(o1[0] * sc / (1.0f + __expf(-bf2f(g1.x))));
    r1.y = f2bf(o1[1] * sc / (1.0f + __expf(-bf2f(g1.y))));
    r1.z = f2bf(o1[2] * sc / (1.0f + __expf(-bf2f(g1.z))));
    r1.w = f2bf(o1[3] * sc / (1.0f + __expf(-bf2f(g1.w))));
    *(ushort4*)&atto[(hb + prow) * 32 + quad * 4] = r0;
    *(ushort4*)&atto[(hb + prow) * 32 + 16 + quad * 4] = r1;
  } else {
    // ================= MHC rows: 6 waves x 4 tiles x 16 rows, 32 keys ====
    const int wid = w - 2;                    // 0..5
    const bf16x8 bk0 = *(const bf16x8*)&Kl[mi][quad * 8];
    const bf16x8 bk1 = *(const bf16x8*)&Kl[16 + mi][quad * 8];
    const bf16x8 bv0 = *(const bf16x8*)&VpT[mi][quad * 8];
    const bf16x8 bv1 = *(const bf16x8*)&VpT[16 + mi][quad * 8];
    const float4 pfa = *(const float4*)&pf[quad * 4];        // keys quad*4+r
    const float4 pfb = *(const float4*)&pf[16 + quad * 4];   // keys 16+quad*4+r
    for (int i = 0; i < 4; ++i) {
      const int rloc = (wid * 4 + i) * 16;          // mhc-local row base
      const size_t grow = hb + 32 + rloc + mi;      // this lane's output row
      const bf16x8 aq = *(const bf16x8*)&Qh[grow * 32 + quad * 8];
      const f32x4 s0 = __builtin_amdgcn_mfma_f32_16x16x32_bf16(bk0, aq, fz, 0, 0, 0);
      const f32x4 s1 = __builtin_amdgcn_mfma_f32_16x16x32_bf16(bk1, aq, fz, 0, 0, 0);
      const float e00 = pfa.x * __expf(s0[0] * SCALE_E);
      const float e01 = pfa.y * __expf(s0[1] * SCALE_E);
      const float e02 = pfa.z * __expf(s0[2] * SCALE_E);
      const float e03 = pfa.w * __expf(s0[3] * SCALE_E);
      const float e10 = pfb.x * __expf(s1[0] * SCALE_E);
      const float e11 = pfb.y * __expf(s1[1] * SCALE_E);
      const float e12 = pfb.z * __expf(s1[2] * SCALE_E);
      const float e13 = pfb.w * __expf(s1[3] * SCALE_E);
      float lsum = ((e00 + e01) + (e02 + e03)) + ((e10 + e11) + (e12 + e13));
      lsum += __shfl_xor(lsum, 16);
      lsum += __shfl_xor(lsum, 32);
      const unsigned pA0 = pk2bf(e00, e01), pA1 = pk2bf(e02, e03);
      const unsigned pB0 = pk2bf(e10, e11), pB1 = pk2bf(e12, e13);
      const unsigned a00 = __shfl(pA0, idxA), a01 = __shfl(pA1, idxA);
      const unsigned b00 = __shfl(pB0, idxA), b01 = __shfl(pB1, idxA);
      const unsigned a10 = __shfl(pA0, idxB), a11 = __shfl(pA1, idxB);
      const unsigned b10 = __shfl(pB0, idxB), b11 = __shfl(pB1, idxB);
      U8 pf_;
      pf_.u[0] = hi ? b00 : a00;
      pf_.u[1] = hi ? b01 : a01;
      pf_.u[2] = hi ? b10 : a10;
      pf_.u[3] = hi ? b11 : a11;
      const f32x4 o0 = __builtin_amdgcn_mfma_f32_16x16x32_bf16(bv0, pf_.v, fz, 0, 0, 0);
      const f32x4 o1 = __builtin_amdgcn_mfma_f32_16x16x32_bf16(bv1, pf_.v, fz, 0, 0, 0);
      const float sc = (1.0f / lsum) * mfl[rloc + mi];
      const ushort4 g0 = *(const ushort4*)&Gh[grow * 32 + quad * 4];
      const ushort4 g1 = *(const ushort4*)&Gh[grow * 32 + 16 + quad * 4];
      ushort4 r0, r1;
      r0.x = f2bf(o0[0] * sc / (1.0f + __expf(-bf2f(g0.x))));
      r0.y = f2bf(o0[1] * sc / (1.0f + __expf(-bf2f(g0.y))));
      r0.z = f2bf(o0[2] * sc / (1.0f + __expf(-bf2f(g0.z))));
      r0.w = f2bf(o0[3] * sc / (1.0f + __expf(-bf2f(g0.w))));
      r1.x = f2bf(o1[0] * sc / (1.0f + __expf(-bf2f(g1.x))));
      r1.y = f2bf(o1[1] * sc / (1.0f + __expf(-bf2f(g1.y))));
      r1.z = f2bf(o1[2] * sc / (1.0f + __expf(-bf2f(g1.z))));
      r1.w = f2bf(o1[3] * sc / (1.0f + __expf(-bf2f(g1.w))));
      *(ushort4*)&atto[grow * 32 + quad * 4] = r0;
      *(ushort4*)&atto[grow * 32 + 16 + quad * 4] = r1;
    }
  }
}

// ---------------------------------------------------------------------------
// GEMM2 + bias + LN2 fused: out = LN(att[53248x256] * WoT^T + bias).
// r8 structure: global_load_lds staging, (512,2).
// A is HEAD-MAJOR atto[h][row][32]; the 16B stage granules never cross a
// head boundary (col = kc + gcol*8, multiples of 8), so only the A address
// computation changes vs row-major.
// ---------------------------------------------------------------------------
__global__ __launch_bounds__(512, 2)
void gemm2_ln(const u16* __restrict__ A, const u16* __restrict__ BT,
              float* __restrict__ out, const float* __restrict__ bias,
              const float* __restrict__ gam, const float* __restrict__ bet) {
  __shared__ __attribute__((aligned(16))) u16 As[128 * 64];
  __shared__ __attribute__((aligned(16))) u16 Bs[256 * 64];
  __shared__ float rsum[128][4];
  __shared__ float rssq[128][4];
  __shared__ float mean_s[128], rstd_s[128];
  const int m0 = blockIdx.x * 128;
  const int tid = threadIdx.x;
  const int lane = tid & 63;
  const int w = tid >> 6;            // 0..7
  const int wr = (w >> 2) * 64;      // 0 / 64
  const int wc = (w & 3) * 64;       // 0,64,128,192
  const int mi = lane & 15;
  const int quad = lane >> 4;
  const int rseg = lane >> 3;
  const int gcol = (lane & 7) ^ rseg;
  f32x4 acc[4][4] = {};
  for (int kc = 0; kc < 256; kc += 64) {
    __syncthreads();
    #pragma unroll
    for (int j = 0; j < 2; ++j) {          // A: 16 segs of 8 rows
      const int seg = w * 2 + j;
      const int r = seg * 8 + rseg;
      const int c = kc + gcol * 8;         // head-major remap
      const u16* ga = &A[((size_t)(c >> 5) * BS_ + (m0 + r)) * 32 + (c & 31)];
      __builtin_amdgcn_global_load_lds((cg_void*)ga, (lds_void*)&As[seg * 512], 16, 0, 0);
    }
    #pragma unroll
    for (int j = 0; j < 4; ++j) {          // B: 32 segs of 8 rows
      const int seg = w * 4 + j;
      const int r = seg * 8 + rseg;
      const u16* gb = &BT[(size_t)r * 256 + kc + gcol * 8];
      __builtin_amdgcn_global_load_lds((cg_void*)gb, (lds_void*)&Bs[seg * 512], 16, 0, 0);
    }
    __syncthreads();
    #pragma unroll
    for (int kt = 0; kt < 2; ++kt) {
      bf16x8 a[4], bb[4];
      #pragma unroll
      for (int i = 0; i < 4; ++i) {
        const int m = wr + i * 16 + mi;
        const int pg = (kt * 4 + quad) ^ (mi & 7);
        a[i] = *(const bf16x8*)&As[m * 64 + pg * 8];
      }
      #pragma unroll
      for (int i = 0; i < 4; ++i) {
        const int n = wc + i * 16 + mi;
        const int pg = (kt * 4 + quad) ^ (mi & 7);
        bb[i] = *(const bf16x8*)&Bs[n * 64 + pg * 8];
      }
      #pragma unroll
      for (int i = 0; i < 4; ++i)
        #pragma unroll
        for (int jn = 0; jn < 4; ++jn)
          acc[i][jn] = __builtin_amdgcn_mfma_f32_16x16x32_bf16(a[i], bb[jn], acc[i][jn], 0, 0, 0);
    }
  }
  // bias per thread-column
  float bia[4];
  #pragma unroll
  for (int jn = 0; jn < 4; ++jn) bia[jn] = bias[wc + jn * 16 + mi];
  // row partial stats: sum over jn, reduce over mi (within quad)
  #pragma unroll
  for (int i = 0; i < 4; ++i) {
    #pragma unroll
    for (int r = 0; r < 4; ++r) {
      float s = 0.0f, qq = 0.0f;
      #pragma unroll
      for (int jn = 0; jn < 4; ++jn) {
        const float v = acc[i][jn][r] + bia[jn];
        s += v; qq += v * v;
      }
      #pragma unroll
      for (int off = 1; off < 16; off <<= 1) {
        s  += __shfl_xor(s, off);
        qq += __shfl_xor(qq, off);
      }
      if (mi == 0) {
        const int rl = wr + i * 16 + quad * 4 + r;
        rsum[rl][w & 3] = s;
        rssq[rl][w & 3] = qq;
      }
    }
  }
  __syncthreads();
  if (tid < 128) {
    const float s = rsum[tid][0] + rsum[tid][1] + rsum[tid][2] + rsum[tid][3];
    const float qq = rssq[tid][0] + rssq[tid][1] + rssq[tid][2] + rssq[tid][3];
    const float mean = s * 0.00390625f;
    float var = qq * 0.00390625f - mean * mean;
    var = fmaxf(var, 0.0f);
    mean_s[tid] = mean;
    rstd_s[tid] = rsqrtf(var + 1e-6f);
  }
  __syncthreads();
  #pragma unroll
  for (int jn = 0; jn < 4; ++jn) {
    const int col = wc + jn * 16 + mi;
    const float gv = gam[col], bv = bet[col];
    #pragma unroll
    for (int i = 0; i < 4; ++i) {
      #pragma unroll
      for (int r = 0; r < 4; ++r) {
        const int rl = wr + i * 16 + quad * 4 + r;
        const float v = acc[i][jn][r] + bia[jn];
        out[(size_t)(m0 + rl) * 256 + col] = (v - mean_s[rl]) * rstd_s[rl] * gv + bv;
      }
    }
  }
}

// ---------------------------------------------------------------------------
// Launch. All d_in fp32; d_out fp32. Workspace:
//   WT   @ 0         : 524288   (bf16)
//   WoT  @ 524288    : 131072   (bf16)
//   xln  @ 655360    : 27262976 (bf16, LN1 out row-major)
//   Qh   @ 27918336  : 27262976 (bf16, [h][row][e] — Q round-trip)
//   atto @ 55181312  : 27262976 (bf16, attention out HEAD-MAJOR [h][row][32])
//   (unused @ 82444288)
//   Gh   @ 109707264 : 27262976 (bf16, [h][row][e] — G round-trip)
// ---------------------------------------------------------------------------
extern "C" void kernel_launch(void* const* d_in, const int* in_sizes, int n_in,
                              void* d_out, int out_size, void* d_ws, size_t ws_size,
                              hipStream_t stream) {
  const float* x      = (const float*)d_in[0];
  const float* p_mask = (const float*)d_in[1];
  const float* m_mask = (const float*)d_in[2];
  const float* q_proj = (const float*)d_in[3];
  const float* k_proj = (const float*)d_in[4];
  const float* v_proj = (const float*)d_in[5];
  const float* g_proj = (const float*)d_in[6];
  const float* out_w  = (const float*)d_in[7];
  const float* out_b  = (const float*)d_in[8];
  const float* ln1_g  = (const float*)d_in[9];
  const float* ln1_b  = (const float*)d_in[10];
  const float* ln2_g  = (const float*)d_in[11];
  const float* ln2_b  = (const float*)d_in[12];

  char* ws = (char*)d_ws;
  u16* WT   = (u16*)(ws);
  u16* WoT  = (u16*)(ws + 524288);
  u16* xln  = (u16*)(ws + 655360);
  u16* Qh   = (u16*)(ws + 27918336);
  u16* atto = (u16*)(ws + 55181312);
  u16* Gh   = (u16*)(ws + 109707264);
  float* outp = (float*)d_out;

  hipLaunchKernelGGL(prep, dim3(1280 + BS_ / 4), dim3(256), 0, stream,
                     q_proj, k_proj, v_proj, g_proj, out_w, WT, WoT,
                     x, xln, ln1_g, ln1_b);
  hipLaunchKernelGGL(qkvg_att, dim3(B_ * H_), dim3(512), 0, stream,
                     xln, WT, Qh, Gh, p_mask, m_mask, atto);
  hipLaunchKernelGGL(gemm2_ln, dim3(BS_ / 128), dim3(512), 0, stream,
                     atto, WoT, outp, out_b, ln2_g, ln2_b);
}